// Round 7
// baseline (3010928.516 us; speedup 1.0000x reference)
//
#include <hip/hip_runtime.h>

// Problem constants
#define BB 256
#define SS 1024
#define II 64
#define HH 256
#define OO 24
#define NG 16     // groups (16 batch rows each)
#define NP 16     // parts per group (64 z-cols = 16 h-dims each)
#define BT 16

typedef __attribute__((ext_vector_type(8))) short short8;
typedef __attribute__((ext_vector_type(4))) float f32x4;
typedef unsigned long long ull;

#define POLL_CAP 65536

// LDS byte offsets; total padded to 96KB to guarantee 1 block/CU
#define A_HI 0          // h hi frags  [8 kstep][64 lane][16B]
#define A_LO 8192
#define Z_OF 16384      // z  [gate q][reg r][lane]  f32   (4KB)
#define E_OF 20480      // energy partials, same layout    (4KB)
#define SMEM_BYTES 98304

#define MFMA(a,b,c) __builtin_amdgcn_mfma_f32_16x16x32_bf16(a,b,c,0,0,0)

__device__ __forceinline__ float fsig(float x)  { return 1.f/(1.f+__expf(-x)); }
__device__ __forceinline__ float ftanh(float x) { return 1.f - 2.f/(__expf(2.f*x)+1.f); }

__device__ __forceinline__ unsigned rne_bf16(float x){
    unsigned u = __float_as_uint(x);
    return (u + 0x7FFFu + ((u>>16)&1u)) >> 16;
}
__device__ __forceinline__ void split_bf(float x, unsigned &hi, unsigned &lo){
    hi = rne_bf16(x);
    lo = rne_bf16(x - __uint_as_float(hi<<16));
}

union U4 { unsigned u[4]; short8 s; };

__device__ __forceinline__ void pack8(const float* v, short8 &H, short8 &L){
    U4 h_, l_;
    #pragma unroll
    for (int i = 0; i < 4; ++i) {
        unsigned a,b,c,d;
        split_bf(v[2*i], a, b); split_bf(v[2*i+1], c, d);
        h_.u[i] = a | (c<<16);
        l_.u[i] = b | (d<<16);
    }
    H = h_.s; L = l_.s;
}

// ---- XCD-local (sc0: bypass L0/L1, served by the shared per-XCD L2) ------
__device__ __forceinline__ unsigned ld_sc0_u32(const unsigned* p){
    unsigned r;
    asm volatile("global_load_dword %0, %1, off sc0\n\ts_waitcnt vmcnt(0)"
                 : "=v"(r) : "v"(p) : "memory");
    return r;
}
__device__ __forceinline__ ull ld_sc0_u64(const ull* p){
    ull r;
    asm volatile("global_load_dwordx2 %0, %1, off sc0\n\ts_waitcnt vmcnt(0)"
                 : "=v"(r) : "v"(p) : "memory");
    return r;
}
__device__ __forceinline__ ull ld_sc0_u64_async(const ull* p){
    ull r;
    asm volatile("global_load_dwordx2 %0, %1, off sc0"
                 : "=v"(r) : "v"(p) : "memory");
    return r;
}
__device__ __forceinline__ void st_sc0_f32(float* p, float v){
    asm volatile("global_store_dword %0, %1, off sc0" :: "v"(p), "v"(v) : "memory");
}
__device__ __forceinline__ void st_sc0_u32(unsigned* p, unsigned v){
    asm volatile("global_store_dword %0, %1, off sc0" :: "v"(p), "v"(v) : "memory");
}
__device__ __forceinline__ void st_sc0_u64(ull* p, ull v){
    asm volatile("global_store_dwordx2 %0, %1, off sc0" :: "v"(p), "v"(v) : "memory");
}

// ---------------------------------------------------------------------------
// Fused xW + LSTM + attention scores + online-softmax context, MFMA bf16x3.
// grid = 256, block = 256 (4 waves). (group,part) assigned DYNAMICALLY from
// HW_REG_XCC_ID so all 16 parts of a group provably share one XCD; the whole
// h/sp/flag exchange then runs at shared-L2 latency via sc0 ops.
// ---------------------------------------------------------------------------
__global__ __launch_bounds__(256, 1)
void lstm_fused_kernel(const float* __restrict__ x,  const float* __restrict__ Wi,
                       const float* __restrict__ Wh, const float* __restrict__ bias,
                       const float* __restrict__ aW, const float* __restrict__ ab,
                       const float* __restrict__ av,
                       float* __restrict__ hgf, ull* __restrict__ spx,
                       unsigned* __restrict__ flags, unsigned* __restrict__ xcd_cnt,
                       float* __restrict__ ctxg)
{
    __shared__ __align__(16) char smem[SMEM_BYTES];
    __shared__ int sdead;
    __shared__ unsigned s_slot;

    const int tid = threadIdx.x;
    const int w = tid >> 6;          // wave = gate index
    const int l = tid & 63;

    // ---- dynamic (group, part) from hardware XCC id ----------------------
    unsigned xcc;
    asm("s_getreg_b32 %0, hwreg(HW_REG_XCC_ID)" : "=s"(xcc));
    if (tid == 0) {
        sdead = 0;
        s_slot = atomicAdd(&xcd_cnt[xcc & 7], 1u);
    }
    __syncthreads();
    const unsigned slot = s_slot & 31;           // trip-wire mask (no OOB)
    const int g = (int)((xcc & 7) * 2 + (slot >> 4));   // 2 groups per XCD
    const int p = (int)(slot & 15);
    const int b0 = g * BT;

    const int n = l & 15;                    // frag col (B) / C col
    const int gcol = w*256 + p*16 + n;       // global z column for this lane
    const int gb = (l>>4)*4 + w;             // owned batch (gate phase)
    const int gd = n;                        // owned h-dim (local, 0..15)

    // ---- init: pre-split B operands into register fragments --------------
    short8 BwhH[8], BwhL[8];
    #pragma unroll
    for (int ks = 0; ks < 8; ++ks) {
        U4 H, L;
        #pragma unroll
        for (int i2 = 0; i2 < 4; ++i2) {
            int k0 = ks*32 + (l>>4)*8 + i2*2;
            unsigned h0,l0,h1,l1;
            split_bf(Wh[(size_t)k0*1024 + gcol], h0, l0);
            split_bf(Wh[(size_t)(k0+1)*1024 + gcol], h1, l1);
            H.u[i2] = h0 | (h1<<16);
            L.u[i2] = l0 | (l1<<16);
        }
        BwhH[ks] = H.s; BwhL[ks] = L.s;
    }
    short8 BwiH[2], BwiL[2];
    #pragma unroll
    for (int ks = 0; ks < 2; ++ks) {
        U4 H, L;
        #pragma unroll
        for (int i2 = 0; i2 < 4; ++i2) {
            int k0 = ks*32 + (l>>4)*8 + i2*2;
            unsigned h0,l0,h1,l1;
            split_bf(Wi[(size_t)k0*1024 + gcol], h0, l0);
            split_bf(Wi[(size_t)(k0+1)*1024 + gcol], h1, l1);
            H.u[i2] = h0 | (h1<<16);
            L.u[i2] = l0 | (l1<<16);
        }
        BwiH[ks] = H.s; BwiL[ks] = L.s;
    }
    short8 BwaH[2], BwaL[2];
    #pragma unroll
    for (int j = 0; j < 2; ++j) {
        int ks = 2*w + j;     // this wave's energy k-steps
        U4 H, L;
        #pragma unroll
        for (int i2 = 0; i2 < 4; ++i2) {
            int k0 = ks*32 + (l>>4)*8 + i2*2;
            unsigned h0,l0,h1,l1;
            split_bf(aW[(size_t)k0*256 + p*16 + n], h0, l0);
            split_bf(aW[(size_t)(k0+1)*256 + p*16 + n], h1, l1);
            H.u[i2] = h0 | (h1<<16);
            L.u[i2] = l0 | (l1<<16);
        }
        BwaH[j] = H.s; BwaL[j] = L.s;
    }
    const float bb  = bias[gcol];
    const float vj  = av[p*16 + gd];
    const float abj = ab[p*16 + gd];

    // h-exchange mapping: thread loads batches pbase,pbase+1 x dim-octet po
    const int po    = tid >> 3;        // 0..31 (dim octet)
    const int pbase = (tid & 7) * 2;   // even batch
    const int wa0 = (po>>2)*1024 + ((po&3)*16 + pbase)*16;
    const int wa1 = wa0 + 16;

    const int xb = l & 15;

    float c_state = 0.f, h1v = 0.f, h2v = 0.f;
    float m_run = -1.0e30f, l_run = 0.f, ctx = 0.f;

    float* zl = (float*)(smem + Z_OF);
    float* el = (float*)(smem + E_OF);
    unsigned* flagg = flags + g * NP;
    const int xoct = l >> 4;           // 0..3: frag k-octet within kstep

    for (int t = 0; t < SS; ++t) {
        // ---- x frags straight from global (no LDS), hides flag spin ------
        const float* xrow = x + ((size_t)(b0 + xb) * SS + t) * II + xoct*8;
        float xv0[8], xv1[8];
        *(float4*)&xv0[0] = *(const float4*)(xrow);
        *(float4*)&xv0[4] = *(const float4*)(xrow + 4);
        *(float4*)&xv1[0] = *(const float4*)(xrow + 32);
        *(float4*)&xv1[4] = *(const float4*)(xrow + 36);
        short8 XH0, XL0, XH1, XL1;
        pack8(xv0, XH0, XL0);
        pack8(xv1, XH1, XL1);

        f32x4 zacc = {bb,bb,bb,bb};
        zacc = MFMA(XH0, BwiH[0], zacc);
        zacc = MFMA(XH0, BwiL[0], zacc);
        zacc = MFMA(XL0, BwiH[0], zacc);
        zacc = MFMA(XH1, BwiH[1], zacc);
        zacc = MFMA(XH1, BwiL[1], zacc);
        zacc = MFMA(XL1, BwiH[1], zacc);

        // ---- acquire h(t-1): flag spin (L2 hops) then coalesced loads ----
        if (t > 0) {
            if (tid < NP && !sdead) {
                int it = 0;
                while (ld_sc0_u32(&flagg[tid]) < (unsigned)t) {
                    if (++it > POLL_CAP) { sdead = 1; break; }
                }
            }
        }
        __syncthreads();                                   // barrier 1

        ull spr = 0;
        ull* spp = spx + (size_t)(t&1)*4096 + g*256 + gb*16 + gd;

        if (t > 0) {
            const ull* hr = (const ull*)(hgf + (size_t)((t-1)&1)*65536) + g*2048;
            ull hv[8];
            #pragma unroll
            for (int j = 0; j < 4; ++j) hv[j]   = ld_sc0_u64_async(hr + pbase*128 + po*4 + j);
            #pragma unroll
            for (int j = 0; j < 4; ++j) hv[4+j] = ld_sc0_u64_async(hr + (pbase+1)*128 + po*4 + j);
            if (t > 1) spr = ld_sc0_u64_async(spp);   // early tagged sp(t-2) load
            asm volatile("s_waitcnt vmcnt(0)" ::: "memory");
            __builtin_amdgcn_sched_barrier(0);

            float va[16];
            #pragma unroll
            for (int j = 0; j < 4; ++j) {
                va[2*j]   = __uint_as_float((unsigned)hv[j]);
                va[2*j+1] = __uint_as_float((unsigned)(hv[j]>>32));
                va[8+2*j]   = __uint_as_float((unsigned)hv[4+j]);
                va[8+2*j+1] = __uint_as_float((unsigned)(hv[4+j]>>32));
            }
            short8 H0,L0,H1,L1;
            pack8(&va[0], H0, L0);
            pack8(&va[8], H1, L1);
            *(short8*)(smem + A_HI + wa0) = H0;
            *(short8*)(smem + A_LO + wa0) = L0;
            *(short8*)(smem + A_HI + wa1) = H1;
            *(short8*)(smem + A_LO + wa1) = L1;
        }
        __syncthreads();                                   // barrier 2

        // ---- MFMA: z += h@Wh, energy partial -----------------------------
        f32x4 zacc1 = {0.f,0.f,0.f,0.f};
        f32x4 eacc  = {0.f,0.f,0.f,0.f};
        if (t > 0) {
            #pragma unroll
            for (int ks = 0; ks < 8; ++ks) {
                short8 ah = *(const short8*)(smem + A_HI + ks*1024 + l*16);
                short8 al = *(const short8*)(smem + A_LO + ks*1024 + l*16);
                if ((ks & 1) == 0) {
                    zacc = MFMA(ah, BwhH[ks], zacc);
                    zacc = MFMA(ah, BwhL[ks], zacc);
                    zacc = MFMA(al, BwhH[ks], zacc);
                } else {
                    zacc1 = MFMA(ah, BwhH[ks], zacc1);
                    zacc1 = MFMA(ah, BwhL[ks], zacc1);
                    zacc1 = MFMA(al, BwhL[ks], zacc1);
                }
                if ((ks>>1) == w) {
                    int jj = ks & 1;
                    eacc = MFMA(ah, BwaH[jj], eacc);
                    eacc = MFMA(ah, BwaL[jj], eacc);
                    eacc = MFMA(al, BwaH[jj], eacc);
                }
            }
        }
        #pragma unroll
        for (int r = 0; r < 4; ++r) zl[w*256 + r*64 + l] = zacc[r] + zacc1[r];
        if (t > 0) {
            #pragma unroll
            for (int r = 0; r < 4; ++r) el[w*256 + r*64 + l] = eacc[r];
        }
        __syncthreads();                                   // barrier 3

        // ---- gates -------------------------------------------------------
        float z0 = zl[0*256 + w*64 + l];
        float z1 = zl[1*256 + w*64 + l];
        float z2 = zl[2*256 + w*64 + l];
        float z3 = zl[3*256 + w*64 + l];
        float ig = fsig(z0), fg = fsig(z1), gv = ftanh(z2), og = fsig(z3);
        c_state = fg*c_state + ig*gv;
        float h = og * ftanh(c_state);

        // ---- publish h(t), drain, release flag (critical path first) ----
        st_sc0_f32(hgf + (size_t)(t&1)*65536 + g*4096 + gb*256 + p*16 + gd, h);
        asm volatile("s_waitcnt vmcnt(0)" ::: "memory");
        __syncthreads();                                   // barrier 4
        if (tid == 0) st_sc0_u32(&flagg[p], (unsigned)(t + 1));

        // ---- off critical path: softmax update t-2, score partial t-1 ----
        if (t > 1) {
            const unsigned texp = (unsigned)(t-1);
            int it = 0;
            while ((unsigned)(spr>>32) != texp && it++ < POLL_CAP) spr = ld_sc0_u64(spp);
            float s = __uint_as_float((unsigned)spr);
            s += __shfl_xor(s,1); s += __shfl_xor(s,2);
            s += __shfl_xor(s,4); s += __shfl_xor(s,8);
            float m_new = fmaxf(m_run, s);
            float sc = __expf(m_run - m_new);
            float wt = __expf(s - m_new);
            l_run = l_run*sc + wt;
            ctx   = ctx*sc + wt*h2v;
            m_run = m_new;
        }
        if (t > 0) {
            float e = el[0*256+w*64+l] + el[1*256+w*64+l]
                    + el[2*256+w*64+l] + el[3*256+w*64+l] + abj;
            float scp = vj * ftanh(e);
            scp += __shfl_xor(scp,1); scp += __shfl_xor(scp,2);
            scp += __shfl_xor(scp,4); scp += __shfl_xor(scp,8);
            if (gd == 0)
                st_sc0_u64(spx + (size_t)((t-1)&1)*4096 + g*256 + gb*16 + p,
                           ((ull)(unsigned)t << 32) | (ull)__float_as_uint(scp));
        }
        h2v = h1v; h1v = h;
    }

    // ---- epilogue A: energy/score for SS-1, softmax update for SS-2 ------
    {
        if (tid < NP && !sdead) {
            int it = 0;
            while (ld_sc0_u32(&flagg[tid]) < (unsigned)SS) {
                if (++it > POLL_CAP) { sdead = 1; break; }
            }
        }
        __syncthreads();

        const ull* hr = (const ull*)(hgf + (size_t)((SS-1)&1)*65536) + g*2048;
        ull hv[8];
        #pragma unroll
        for (int j = 0; j < 4; ++j) hv[j]   = ld_sc0_u64_async(hr + pbase*128 + po*4 + j);
        #pragma unroll
        for (int j = 0; j < 4; ++j) hv[4+j] = ld_sc0_u64_async(hr + (pbase+1)*128 + po*4 + j);
        asm volatile("s_waitcnt vmcnt(0)" ::: "memory");
        __builtin_amdgcn_sched_barrier(0);
        float va[16];
        #pragma unroll
        for (int j = 0; j < 4; ++j) {
            va[2*j]     = __uint_as_float((unsigned)hv[j]);
            va[2*j+1]   = __uint_as_float((unsigned)(hv[j]>>32));
            va[8+2*j]   = __uint_as_float((unsigned)hv[4+j]);
            va[8+2*j+1] = __uint_as_float((unsigned)(hv[4+j]>>32));
        }
        short8 H0,L0,H1,L1;
        pack8(&va[0], H0, L0);
        pack8(&va[8], H1, L1);
        *(short8*)(smem + A_HI + wa0) = H0;
        *(short8*)(smem + A_LO + wa0) = L0;
        *(short8*)(smem + A_HI + wa1) = H1;
        *(short8*)(smem + A_LO + wa1) = L1;
        __syncthreads();

        f32x4 eacc = {0.f,0.f,0.f,0.f};
        #pragma unroll
        for (int ks = 0; ks < 8; ++ks) {
            if ((ks>>1) == w) {
                short8 ah = *(const short8*)(smem + A_HI + ks*1024 + l*16);
                short8 al = *(const short8*)(smem + A_LO + ks*1024 + l*16);
                int jj = ks & 1;
                eacc = MFMA(ah, BwaH[jj], eacc);
                eacc = MFMA(ah, BwaL[jj], eacc);
                eacc = MFMA(al, BwaH[jj], eacc);
            }
        }
        #pragma unroll
        for (int r = 0; r < 4; ++r) el[w*256 + r*64 + l] = eacc[r];
        __syncthreads();

        {   // softmax update for SS-2 (sp tagged SS-1, slot (SS-2)&1 == SS&1)
            ull* spp = spx + (size_t)(SS&1)*4096 + g*256 + gb*16 + gd;
            ull spr = ld_sc0_u64(spp);
            const unsigned texp = (unsigned)(SS-1);
            int it = 0;
            while ((unsigned)(spr>>32) != texp && it++ < POLL_CAP) spr = ld_sc0_u64(spp);
            float s = __uint_as_float((unsigned)spr);
            s += __shfl_xor(s,1); s += __shfl_xor(s,2);
            s += __shfl_xor(s,4); s += __shfl_xor(s,8);
            float m_new = fmaxf(m_run, s);
            float sc = __expf(m_run - m_new);
            float wt = __expf(s - m_new);
            l_run = l_run*sc + wt;
            ctx   = ctx*sc + wt*h2v;
            m_run = m_new;
        }
        h2v = h1v;
        // score for SS-1 (tag SS)
        float e = el[0*256+w*64+l] + el[1*256+w*64+l]
                + el[2*256+w*64+l] + el[3*256+w*64+l] + abj;
        float scp = vj * ftanh(e);
        scp += __shfl_xor(scp,1); scp += __shfl_xor(scp,2);
        scp += __shfl_xor(scp,4); scp += __shfl_xor(scp,8);
        if (gd == 0)
            st_sc0_u64(spx + (size_t)((SS-1)&1)*4096 + g*256 + gb*16 + p,
                       ((ull)(unsigned)SS << 32) | (ull)__float_as_uint(scp));
    }

    // ---- epilogue B: softmax update for SS-1, write context --------------
    {
        ull* spp = spx + (size_t)((SS-1)&1)*4096 + g*256 + gb*16 + gd;
        ull spr = ld_sc0_u64(spp);
        const unsigned texp = (unsigned)SS;
        int it = 0;
        while ((unsigned)(spr>>32) != texp && it++ < POLL_CAP) spr = ld_sc0_u64(spp);
        float s = __uint_as_float((unsigned)spr);
        s += __shfl_xor(s,1); s += __shfl_xor(s,2);
        s += __shfl_xor(s,4); s += __shfl_xor(s,8);
        float m_new = fmaxf(m_run, s);
        float sc = __expf(m_run - m_new);
        float wt = __expf(s - m_new);
        l_run = l_run*sc + wt;
        ctx   = ctx*sc + wt*h2v;   // h2v == h(SS-1)

        ctxg[(size_t)(b0+gb)*HH + p*16 + gd] = ctx / l_run;
    }
}

// ---------------------------------------------------------------------------
__global__ __launch_bounds__(64)
void finalize_kernel(const float* __restrict__ ctxg, const float* __restrict__ fcW,
                     const float* __restrict__ fcb, float* __restrict__ out)
{
    __shared__ float cs[HH];
    const int b = blockIdx.x, tid = threadIdx.x;
    *(float4*)&cs[tid*4] = *(const float4*)&ctxg[(size_t)b*HH + tid*4];
    __syncthreads();
    if (tid < OO) {
        float a = fcb[tid];
        #pragma unroll 8
        for (int d = 0; d < HH; ++d) a = fmaf(cs[d], fcW[d*OO + tid], a);
        out[b*OO + tid] = a;
    }
}

// ---------------------------------------------------------------------------
extern "C" void kernel_launch(void* const* d_in, const int* in_sizes, int n_in,
                              void* d_out, int out_size, void* d_ws, size_t ws_size,
                              hipStream_t stream)
{
    const float* x      = (const float*)d_in[0];
    const float* Wi     = (const float*)d_in[1];
    const float* Wh     = (const float*)d_in[2];
    const float* bias   = (const float*)d_in[3];
    const float* attn_W = (const float*)d_in[4];
    const float* attn_b = (const float*)d_in[5];
    const float* v      = (const float*)d_in[6];
    const float* fc_W   = (const float*)d_in[7];
    const float* fc_b   = (const float*)d_in[8];
    float* out = (float*)d_out;

    // workspace ~850KB: h ring + tagged sp ring + flags + xcd counters + ctx
    float* hgf = (float*)d_ws;                       // 131072 f        (512KB)
    ull*   spx = (ull*)(hgf + 131072);               // 8192 ull        (64KB)
    unsigned* flags = (unsigned*)(spx + 8192);       // 256 u32         (1KB)
    unsigned* xcd_cnt = flags + 256;                 // 8 u32           (32B)
    float* ctxg = (float*)(xcd_cnt + 8);             // 65536 f  (16B-aligned)

    // zero sp tags + flags + xcd counters each launch (graph-replay safe)
    hipMemsetAsync(spx, 0, 8192*sizeof(ull) + 256*sizeof(unsigned) + 8*sizeof(unsigned), stream);

    lstm_fused_kernel<<<dim3(NG*NP), dim3(256), 0, stream>>>(
        x, Wi, Wh, bias, attn_W, attn_b, v, hgf, spx, flags, xcd_cnt, ctxg);
    finalize_kernel<<<dim3(BB), dim3(64), 0, stream>>>(ctxg, fc_W, fc_b, out);
}

// Round 8
// 4801.729 us; speedup vs baseline: 627.0509x; 627.0509x over previous
//
#include <hip/hip_runtime.h>

// Problem constants
#define BB 256
#define SS 1024
#define II 64
#define HH 256
#define OO 24
#define NG 16     // groups (16 batch rows each)
#define NP 16     // parts per group (64 z-cols = 16 h-dims each)
#define BT 16

typedef __attribute__((ext_vector_type(8))) short short8;
typedef __attribute__((ext_vector_type(4))) float f32x4;
typedef unsigned long long ull;

#define H_ROUND_CAP 1024   // parallel retry rounds per step (latches sdead)
#define SP_CAP      2048

// LDS: parity-double-buffered regions; padded to 96KB -> 1 block/CU
#define A_HI(par) ((par)*16384)
#define A_LO(par) ((par)*16384 + 8192)
#define Z_OF(par) (32768 + (par)*8192)
#define E_OF(par) (32768 + (par)*8192 + 4096)
#define SMEM_BYTES 98304

#define MFMA(a,b,c) __builtin_amdgcn_mfma_f32_16x16x32_bf16(a,b,c,0,0,0)

__device__ __forceinline__ float fsig(float x)  { return 1.f/(1.f+__expf(-x)); }
__device__ __forceinline__ float ftanh(float x) { return 1.f - 2.f/(__expf(2.f*x)+1.f); }

__device__ __forceinline__ unsigned rne_bf16(float x){
    unsigned u = __float_as_uint(x);
    return (u + 0x7FFFu + ((u>>16)&1u)) >> 16;
}
__device__ __forceinline__ void split_bf(float x, unsigned &hi, unsigned &lo){
    hi = rne_bf16(x);
    lo = rne_bf16(x - __uint_as_float(hi<<16));
}

union U4 { unsigned u[4]; short8 s; };

__device__ __forceinline__ void pack8(const float* v, short8 &H, short8 &L){
    U4 h_, l_;
    #pragma unroll
    for (int i = 0; i < 4; ++i) {
        unsigned a,b,c,d;
        split_bf(v[2*i], a, b); split_bf(v[2*i+1], c, d);
        h_.u[i] = a | (c<<16);
        l_.u[i] = b | (d<<16);
    }
    H = h_.s; L = l_.s;
}

// AGENT-scope relaxed atomics (proven coherent+fast in r3/r4/r6)
__device__ __forceinline__ ull cld(const ull* p){
    return __hip_atomic_load(p, __ATOMIC_RELAXED, __HIP_MEMORY_SCOPE_AGENT);
}
__device__ __forceinline__ void cst(ull* p, ull v){
    __hip_atomic_store(p, v, __ATOMIC_RELAXED, __HIP_MEMORY_SCOPE_AGENT);
}

// ---------------------------------------------------------------------------
// Fused xW + LSTM + attention scores + online-softmax context, MFMA bf16x3.
// grid = 256 (16 groups x 16 parts), block = 256 (4 waves).
// h exchange: tagged 8B (val,tag) words, fire-and-forget stores, consumer
// parallel-batch loads with per-round tag check (no flags, no drains).
// ---------------------------------------------------------------------------
__global__ __launch_bounds__(256, 1)
void lstm_fused_kernel(const float* __restrict__ x,  const float* __restrict__ Wi,
                       const float* __restrict__ Wh, const float* __restrict__ bias,
                       const float* __restrict__ aW, const float* __restrict__ ab,
                       const float* __restrict__ av,
                       ull* __restrict__ hx, ull* __restrict__ spx,
                       float* __restrict__ ctxg)
{
    __shared__ __align__(16) char smem[SMEM_BYTES];
    __shared__ int sdead;

    const int tid = threadIdx.x;
    const int w = tid >> 6;          // wave = gate index
    const int l = tid & 63;
    const int p = blockIdx.x >> 4;   // part
    const int g = blockIdx.x & 15;   // group
    const int b0 = g * BT;

    if (tid == 0) sdead = 0;
    __syncthreads();

    const int n = l & 15;                    // frag col (B) / C col
    const int gcol = w*256 + p*16 + n;       // global z column for this lane
    const int gb = (l>>4)*4 + w;             // owned batch (gate phase)
    const int gd = n;                        // owned h-dim (local, 0..15)

    // ---- init: pre-split B operands into register fragments --------------
    short8 BwhH[8], BwhL[8];
    #pragma unroll
    for (int ks = 0; ks < 8; ++ks) {
        U4 H, L;
        #pragma unroll
        for (int i2 = 0; i2 < 4; ++i2) {
            int k0 = ks*32 + (l>>4)*8 + i2*2;
            unsigned h0,l0,h1,l1;
            split_bf(Wh[(size_t)k0*1024 + gcol], h0, l0);
            split_bf(Wh[(size_t)(k0+1)*1024 + gcol], h1, l1);
            H.u[i2] = h0 | (h1<<16);
            L.u[i2] = l0 | (l1<<16);
        }
        BwhH[ks] = H.s; BwhL[ks] = L.s;
    }
    short8 BwiH[2], BwiL[2];
    #pragma unroll
    for (int ks = 0; ks < 2; ++ks) {
        U4 H, L;
        #pragma unroll
        for (int i2 = 0; i2 < 4; ++i2) {
            int k0 = ks*32 + (l>>4)*8 + i2*2;
            unsigned h0,l0,h1,l1;
            split_bf(Wi[(size_t)k0*1024 + gcol], h0, l0);
            split_bf(Wi[(size_t)(k0+1)*1024 + gcol], h1, l1);
            H.u[i2] = h0 | (h1<<16);
            L.u[i2] = l0 | (l1<<16);
        }
        BwiH[ks] = H.s; BwiL[ks] = L.s;
    }
    short8 BwaH[2], BwaL[2];
    #pragma unroll
    for (int j = 0; j < 2; ++j) {
        int ks = 2*w + j;     // this wave's energy k-steps
        U4 H, L;
        #pragma unroll
        for (int i2 = 0; i2 < 4; ++i2) {
            int k0 = ks*32 + (l>>4)*8 + i2*2;
            unsigned h0,l0,h1,l1;
            split_bf(aW[(size_t)k0*256 + p*16 + n], h0, l0);
            split_bf(aW[(size_t)(k0+1)*256 + p*16 + n], h1, l1);
            H.u[i2] = h0 | (h1<<16);
            L.u[i2] = l0 | (l1<<16);
        }
        BwaH[j] = H.s; BwaL[j] = L.s;
    }
    const float bb  = bias[gcol];
    const float vj  = av[p*16 + gd];
    const float abj = ab[p*16 + gd];

    // consumer mapping: thread (po = dim octet 0..31, pbase = even batch)
    const int po    = tid >> 3;
    const int pbase = (tid & 7) * 2;
    const int q     = po >> 1;          // producer part of this octet
    const int gd0   = (po & 1) * 8;     // local dim base
    const int wa0 = (po>>2)*1024 + ((po&3)*16 + pbase)*16;
    const int wa1 = wa0 + 16;

    const int xb = l & 15;
    const int xoct = l >> 4;

    float c_state = 0.f, h1v = 0.f, h2v = 0.f;
    float m_run = -1.0e30f, l_run = 0.f, ctx = 0.f;

    for (int t = 0; t < SS; ++t) {
        const int par = t & 1;
        // ---- x loads FIRST (so their wait doesn't drain the h loads) -----
        const float* xrow = x + ((size_t)(b0 + xb) * SS + t) * II + xoct*8;
        float xv0[8], xv1[8];
        *(float4*)&xv0[0] = *(const float4*)(xrow);
        *(float4*)&xv0[4] = *(const float4*)(xrow + 4);
        *(float4*)&xv1[0] = *(const float4*)(xrow + 32);
        *(float4*)&xv1[4] = *(const float4*)(xrow + 36);

        // ---- tagged h(t-1) loads: parallel batch issue -------------------
        ull hv[16]; ull spr = 0;
        const ull* hb0 = hx;  const ull* hb1 = hx;
        if (t > 0) {
            const ull* hg_ = hx + (size_t)((t-1)&1)*(NG*4096) + g*4096;
            hb0 = hg_ + q*256 + pbase*16 + gd0;
            hb1 = hb0 + 16;
            #pragma unroll
            for (int j = 0; j < 8; ++j) hv[j]   = cld(hb0 + j);
            #pragma unroll
            for (int j = 0; j < 8; ++j) hv[8+j] = cld(hb1 + j);
        }
        ull* spp = spx + (size_t)par*4096 + g*256 + gb*16 + gd;
        if (t > 1) spr = cld(spp);

        // ---- x pack + x MFMA (overlaps h-load flight) --------------------
        short8 XH0, XL0, XH1, XL1;
        pack8(xv0, XH0, XL0);
        pack8(xv1, XH1, XL1);
        f32x4 zacc = {bb,bb,bb,bb};
        zacc = MFMA(XH0, BwiH[0], zacc);
        zacc = MFMA(XH0, BwiL[0], zacc);
        zacc = MFMA(XL0, BwiH[0], zacc);
        zacc = MFMA(XH1, BwiH[1], zacc);
        zacc = MFMA(XH1, BwiL[1], zacc);
        zacc = MFMA(XL1, BwiH[1], zacc);

        // ---- tag check + parallel retry rounds ---------------------------
        if (t > 0) {
            const unsigned texp = (unsigned)t;   // h(t-1) tagged t
            unsigned need = 0xFFFFu;
            int rounds = 0;
            while (true) {
                unsigned nn = 0;
                #pragma unroll
                for (int e = 0; e < 16; ++e)
                    if (need & (1u<<e))
                        if ((unsigned)(hv[e]>>32) != texp) nn |= (1u<<e);
                need = nn;
                if (!need || sdead) break;
                if (++rounds > H_ROUND_CAP) { sdead = 1; break; }
                #pragma unroll
                for (int e = 0; e < 16; ++e)
                    if (need & (1u<<e))
                        hv[e] = cld(e < 8 ? hb0 + e : hb1 + (e-8));
            }
            float va[16];
            #pragma unroll
            for (int e = 0; e < 16; ++e) va[e] = __uint_as_float((unsigned)hv[e]);
            short8 H0,L0,H1,L1;
            pack8(&va[0], H0, L0);
            pack8(&va[8], H1, L1);
            *(short8*)(smem + A_HI(par) + wa0) = H0;
            *(short8*)(smem + A_LO(par) + wa0) = L0;
            *(short8*)(smem + A_HI(par) + wa1) = H1;
            *(short8*)(smem + A_LO(par) + wa1) = L1;
        }
        __syncthreads();                                   // barrier 1

        // ---- MFMA: z += h@Wh, energy partial -----------------------------
        f32x4 zacc1 = {0.f,0.f,0.f,0.f};
        f32x4 eacc  = {0.f,0.f,0.f,0.f};
        if (t > 0) {
            #pragma unroll
            for (int ks = 0; ks < 8; ++ks) {
                short8 ah = *(const short8*)(smem + A_HI(par) + ks*1024 + l*16);
                short8 al = *(const short8*)(smem + A_LO(par) + ks*1024 + l*16);
                if ((ks & 1) == 0) {
                    zacc = MFMA(ah, BwhH[ks], zacc);
                    zacc = MFMA(ah, BwhL[ks], zacc);
                    zacc = MFMA(al, BwhH[ks], zacc);
                } else {
                    zacc1 = MFMA(ah, BwhH[ks], zacc1);
                    zacc1 = MFMA(ah, BwhL[ks], zacc1);
                    zacc1 = MFMA(al, BwhH[ks], zacc1);
                }
                if ((ks>>1) == w) {
                    int jj = ks & 1;
                    eacc = MFMA(ah, BwaH[jj], eacc);
                    eacc = MFMA(ah, BwaL[jj], eacc);
                    eacc = MFMA(al, BwaH[jj], eacc);
                }
            }
        }
        float* zl = (float*)(smem + Z_OF(par));
        float* el = (float*)(smem + E_OF(par));
        #pragma unroll
        for (int r = 0; r < 4; ++r) zl[w*256 + r*64 + l] = zacc[r] + zacc1[r];
        if (t > 0) {
            #pragma unroll
            for (int r = 0; r < 4; ++r) el[w*256 + r*64 + l] = eacc[r];
        }
        __syncthreads();                                   // barrier 2

        // ---- gates -------------------------------------------------------
        float z0 = zl[0*256 + w*64 + l];
        float z1 = zl[1*256 + w*64 + l];
        float z2 = zl[2*256 + w*64 + l];
        float z3 = zl[3*256 + w*64 + l];
        float ig = fsig(z0), fg = fsig(z1), gv = ftanh(z2), og = fsig(z3);
        c_state = fg*c_state + ig*gv;
        float h = og * ftanh(c_state);

        // ---- publish h(t) tagged t+1, fire-and-forget (critical path) ----
        cst(hx + (size_t)par*(NG*4096) + g*4096 + p*256 + gb*16 + gd,
            ((ull)(unsigned)(t+1) << 32) | (ull)__float_as_uint(h));

        // ---- off critical path: score partial t-1, softmax update t-2 ----
        if (t > 0) {
            float e = el[0*256+w*64+l] + el[1*256+w*64+l]
                    + el[2*256+w*64+l] + el[3*256+w*64+l] + abj;
            float scp = vj * ftanh(e);
            scp += __shfl_xor(scp,1); scp += __shfl_xor(scp,2);
            scp += __shfl_xor(scp,4); scp += __shfl_xor(scp,8);
            if (gd == 0)
                cst(spx + (size_t)((t-1)&1)*4096 + g*256 + gb*16 + p,
                    ((ull)(unsigned)t << 32) | (ull)__float_as_uint(scp));
        }
        if (t > 1) {
            const unsigned texp = (unsigned)(t-1);
            int it = 0;
            while ((unsigned)(spr>>32) != texp) {
                if (sdead || ++it > SP_CAP) { sdead = 1; break; }
                spr = cld(spp);
            }
            float s = __uint_as_float((unsigned)spr);
            s += __shfl_xor(s,1); s += __shfl_xor(s,2);
            s += __shfl_xor(s,4); s += __shfl_xor(s,8);
            float m_new = fmaxf(m_run, s);
            float sc = __expf(m_run - m_new);
            float wt = __expf(s - m_new);
            l_run = l_run*sc + wt;
            ctx   = ctx*sc + wt*h2v;
            m_run = m_new;
        }
        h2v = h1v; h1v = h;
    }

    // ---- epilogue A: energy/score for SS-1, softmax update for SS-2 ------
    {
        const int par = SS & 1;    // 0
        const ull* hg_ = hx + (size_t)((SS-1)&1)*(NG*4096) + g*4096;
        const ull* hb0 = hg_ + q*256 + pbase*16 + gd0;
        const ull* hb1 = hb0 + 16;
        ull hv[16];
        #pragma unroll
        for (int j = 0; j < 8; ++j) hv[j]   = cld(hb0 + j);
        #pragma unroll
        for (int j = 0; j < 8; ++j) hv[8+j] = cld(hb1 + j);
        const unsigned texp = (unsigned)SS;
        unsigned need = 0xFFFFu;
        int rounds = 0;
        while (true) {
            unsigned nn = 0;
            #pragma unroll
            for (int e = 0; e < 16; ++e)
                if (need & (1u<<e))
                    if ((unsigned)(hv[e]>>32) != texp) nn |= (1u<<e);
            need = nn;
            if (!need || sdead) break;
            if (++rounds > H_ROUND_CAP) { sdead = 1; break; }
            #pragma unroll
            for (int e = 0; e < 16; ++e)
                if (need & (1u<<e))
                    hv[e] = cld(e < 8 ? hb0 + e : hb1 + (e-8));
        }
        float va[16];
        #pragma unroll
        for (int e = 0; e < 16; ++e) va[e] = __uint_as_float((unsigned)hv[e]);
        short8 H0,L0,H1,L1;
        pack8(&va[0], H0, L0);
        pack8(&va[8], H1, L1);
        *(short8*)(smem + A_HI(par) + wa0) = H0;
        *(short8*)(smem + A_LO(par) + wa0) = L0;
        *(short8*)(smem + A_HI(par) + wa1) = H1;
        *(short8*)(smem + A_LO(par) + wa1) = L1;
        __syncthreads();

        f32x4 eacc = {0.f,0.f,0.f,0.f};
        #pragma unroll
        for (int ks = 0; ks < 8; ++ks) {
            if ((ks>>1) == w) {
                short8 ah = *(const short8*)(smem + A_HI(par) + ks*1024 + l*16);
                short8 al = *(const short8*)(smem + A_LO(par) + ks*1024 + l*16);
                int jj = ks & 1;
                eacc = MFMA(ah, BwaH[jj], eacc);
                eacc = MFMA(ah, BwaL[jj], eacc);
                eacc = MFMA(al, BwaH[jj], eacc);
            }
        }
        float* el = (float*)(smem + E_OF(par));
        #pragma unroll
        for (int r = 0; r < 4; ++r) el[w*256 + r*64 + l] = eacc[r];
        __syncthreads();

        {   // softmax update for SS-2 (sp slot (SS-2)&1 == SS&1, tag SS-1)
            ull* spp2 = spx + (size_t)(SS&1)*4096 + g*256 + gb*16 + gd;
            ull spr = cld(spp2);
            const unsigned te2 = (unsigned)(SS-1);
            int it = 0;
            while ((unsigned)(spr>>32) != te2) {
                if (sdead || ++it > SP_CAP) { sdead = 1; break; }
                spr = cld(spp2);
            }
            float s = __uint_as_float((unsigned)spr);
            s += __shfl_xor(s,1); s += __shfl_xor(s,2);
            s += __shfl_xor(s,4); s += __shfl_xor(s,8);
            float m_new = fmaxf(m_run, s);
            float sc = __expf(m_run - m_new);
            float wt = __expf(s - m_new);
            l_run = l_run*sc + wt;
            ctx   = ctx*sc + wt*h2v;
            m_run = m_new;
        }
        h2v = h1v;
        // score for SS-1 (tag SS)
        float e = el[0*256+w*64+l] + el[1*256+w*64+l]
                + el[2*256+w*64+l] + el[3*256+w*64+l] + abj;
        float scp = vj * ftanh(e);
        scp += __shfl_xor(scp,1); scp += __shfl_xor(scp,2);
        scp += __shfl_xor(scp,4); scp += __shfl_xor(scp,8);
        if (gd == 0)
            cst(spx + (size_t)((SS-1)&1)*4096 + g*256 + gb*16 + p,
                ((ull)(unsigned)SS << 32) | (ull)__float_as_uint(scp));
    }

    // ---- epilogue B: softmax update for SS-1, write context --------------
    {
        ull* spp2 = spx + (size_t)((SS-1)&1)*4096 + g*256 + gb*16 + gd;
        ull spr = cld(spp2);
        const unsigned texp = (unsigned)SS;
        int it = 0;
        while ((unsigned)(spr>>32) != texp) {
            if (sdead || ++it > SP_CAP) { sdead = 1; break; }
            spr = cld(spp2);
        }
        float s = __uint_as_float((unsigned)spr);
        s += __shfl_xor(s,1); s += __shfl_xor(s,2);
        s += __shfl_xor(s,4); s += __shfl_xor(s,8);
        float m_new = fmaxf(m_run, s);
        float sc = __expf(m_run - m_new);
        float wt = __expf(s - m_new);
        l_run = l_run*sc + wt;
        ctx   = ctx*sc + wt*h2v;   // h2v == h(SS-1)

        ctxg[(size_t)(b0+gb)*HH + p*16 + gd] = ctx / l_run;
    }
}

// ---------------------------------------------------------------------------
__global__ __launch_bounds__(64)
void finalize_kernel(const float* __restrict__ ctxg, const float* __restrict__ fcW,
                     const float* __restrict__ fcb, float* __restrict__ out)
{
    __shared__ float cs[HH];
    const int b = blockIdx.x, tid = threadIdx.x;
    *(float4*)&cs[tid*4] = *(const float4*)&ctxg[(size_t)b*HH + tid*4];
    __syncthreads();
    if (tid < OO) {
        float a = fcb[tid];
        #pragma unroll 8
        for (int d = 0; d < HH; ++d) a = fmaf(cs[d], fcW[d*OO + tid], a);
        out[b*OO + tid] = a;
    }
}

// ---------------------------------------------------------------------------
extern "C" void kernel_launch(void* const* d_in, const int* in_sizes, int n_in,
                              void* d_out, int out_size, void* d_ws, size_t ws_size,
                              hipStream_t stream)
{
    const float* x      = (const float*)d_in[0];
    const float* Wi     = (const float*)d_in[1];
    const float* Wh     = (const float*)d_in[2];
    const float* bias   = (const float*)d_in[3];
    const float* attn_W = (const float*)d_in[4];
    const float* attn_b = (const float*)d_in[5];
    const float* v      = (const float*)d_in[6];
    const float* fc_W   = (const float*)d_in[7];
    const float* fc_b   = (const float*)d_in[8];
    float* out = (float*)d_out;

    // workspace: tagged h ring (1MB) + tagged sp ring (64KB) + ctx
    ull*   hx   = (ull*)d_ws;                  // 2*NG*4096 = 131072 ull
    ull*   spx  = hx + 2*NG*4096;              // 2*NG*256  = 8192 ull
    float* ctxg = (float*)(spx + 8192);        // 65536 floats

    // zero all tags each launch (graph-replay + poison safe)
    hipMemsetAsync(hx, 0, (2*NG*4096 + 8192) * sizeof(ull), stream);

    lstm_fused_kernel<<<dim3(NG*NP), dim3(256), 0, stream>>>(
        x, Wi, Wh, bias, attn_W, attn_b, v, hx, spx, ctxg);
    finalize_kernel<<<dim3(BB), dim3(64), 0, stream>>>(ctxg, fc_W, fc_b, out);
}

// Round 10
// 3524.147 us; speedup vs baseline: 854.3709x; 1.3625x over previous
//
#include <hip/hip_runtime.h>

// Problem constants
#define BB 256
#define SS 1024
#define II 64
#define HH 256
#define OO 24
#define NG 16     // groups (16 batch rows each)
#define NP 16     // parts per group (64 z-cols = 16 h-dims each)
#define BT 16

typedef __attribute__((ext_vector_type(8))) short short8;
typedef __attribute__((ext_vector_type(4))) float f32x4;
typedef unsigned long long ull;

#define H_CAP  8192    // h tag-retry rounds (latches sdead)
#define SP_CAP 16384   // sp spin iterations (latches sdead)

// LDS byte offsets; total padded to 96KB to guarantee 1 block/CU
#define A_HI 0          // h hi frags  [8 kstep][64 lane][16B]
#define A_LO 8192
#define Z_OF 16384      // z  [gate q][reg r][lane]  f32   (4KB)
#define E_OF 20480      // energy partials, same layout    (4KB)
#define SMEM_BYTES 98304

#define MFMA(a,b,c) __builtin_amdgcn_mfma_f32_16x16x32_bf16(a,b,c,0,0,0)

__device__ __forceinline__ float fsig(float x)  { return 1.f/(1.f+__expf(-x)); }
__device__ __forceinline__ float ftanh(float x) { return 1.f - 2.f/(__expf(2.f*x)+1.f); }

__device__ __forceinline__ unsigned rne_bf16(float x){
    unsigned u = __float_as_uint(x);
    return (u + 0x7FFFu + ((u>>16)&1u)) >> 16;
}
__device__ __forceinline__ void split_bf(float x, unsigned &hi, unsigned &lo){
    hi = rne_bf16(x);
    lo = rne_bf16(x - __uint_as_float(hi<<16));
}

union U4 { unsigned u[4]; short8 s; };

__device__ __forceinline__ void pack8(const float* v, short8 &H, short8 &L){
    U4 h_, l_;
    #pragma unroll
    for (int i = 0; i < 4; ++i) {
        unsigned a,b,c,d;
        split_bf(v[2*i], a, b); split_bf(v[2*i+1], c, d);
        h_.u[i] = a | (c<<16);
        l_.u[i] = b | (d<<16);
    }
    H = h_.s; L = l_.s;
}

// AGENT-scope relaxed atomics (the only scheme proven deterministic: r3/r4/r6/r8)
__device__ __forceinline__ ull cld(const ull* p){
    return __hip_atomic_load(p, __ATOMIC_RELAXED, __HIP_MEMORY_SCOPE_AGENT);
}
__device__ __forceinline__ void cst(ull* p, ull v){
    __hip_atomic_store(p, v, __ATOMIC_RELAXED, __HIP_MEMORY_SCOPE_AGENT);
}

// ---------------------------------------------------------------------------
// Fused xW + LSTM + attention scores + online-softmax context, MFMA bf16x3.
// grid = 256 (16 groups x 16 parts), block = 256 (4 waves).
// h exchange: tagged 8B words in CONSUMER-INTERLEAVED layout
//   hx[par][g][j][thread]  (j = 0..15)
// -> consumer load instruction j is fully coalesced (256 threads x 8B
//    contiguous); producer does one scattered fire-and-forget store.
// No flags, no producer drain, 2 barriers/step (vs r6's 4).
// ---------------------------------------------------------------------------
__global__ __launch_bounds__(256, 1)
void lstm_fused_kernel(const float* __restrict__ x,  const float* __restrict__ Wi,
                       const float* __restrict__ Wh, const float* __restrict__ bias,
                       const float* __restrict__ aW, const float* __restrict__ ab,
                       const float* __restrict__ av,
                       ull* __restrict__ hx, ull* __restrict__ spx,
                       float* __restrict__ ctxg)
{
    __shared__ __align__(16) char smem[SMEM_BYTES];
    __shared__ int sdead;

    const int tid = threadIdx.x;
    const int w = tid >> 6;          // wave = gate index
    const int l = tid & 63;
    const int p = blockIdx.x >> 4;   // part
    const int g = blockIdx.x & 15;   // group
    const int b0 = g * BT;

    if (tid == 0) sdead = 0;
    __syncthreads();

    const int n = l & 15;                    // frag col (B) / C col
    const int gcol = w*256 + p*16 + n;       // global z column for this lane
    const int gb = (l>>4)*4 + w;             // owned batch (gate phase)
    const int gd = n;                        // owned h-dim (local, 0..15)

    // ---- init: pre-split B operands into register fragments --------------
    short8 BwhH[8], BwhL[8];
    #pragma unroll
    for (int ks = 0; ks < 8; ++ks) {
        U4 H, L;
        #pragma unroll
        for (int i2 = 0; i2 < 4; ++i2) {
            int k0 = ks*32 + (l>>4)*8 + i2*2;
            unsigned h0,l0,h1,l1;
            split_bf(Wh[(size_t)k0*1024 + gcol], h0, l0);
            split_bf(Wh[(size_t)(k0+1)*1024 + gcol], h1, l1);
            H.u[i2] = h0 | (h1<<16);
            L.u[i2] = l0 | (l1<<16);
        }
        BwhH[ks] = H.s; BwhL[ks] = L.s;
    }
    short8 BwiH[2], BwiL[2];
    #pragma unroll
    for (int ks = 0; ks < 2; ++ks) {
        U4 H, L;
        #pragma unroll
        for (int i2 = 0; i2 < 4; ++i2) {
            int k0 = ks*32 + (l>>4)*8 + i2*2;
            unsigned h0,l0,h1,l1;
            split_bf(Wi[(size_t)k0*1024 + gcol], h0, l0);
            split_bf(Wi[(size_t)(k0+1)*1024 + gcol], h1, l1);
            H.u[i2] = h0 | (h1<<16);
            L.u[i2] = l0 | (l1<<16);
        }
        BwiH[ks] = H.s; BwiL[ks] = L.s;
    }
    short8 BwaH[2], BwaL[2];
    #pragma unroll
    for (int j = 0; j < 2; ++j) {
        int ks = 2*w + j;     // this wave's energy k-steps
        U4 H, L;
        #pragma unroll
        for (int i2 = 0; i2 < 4; ++i2) {
            int k0 = ks*32 + (l>>4)*8 + i2*2;
            unsigned h0,l0,h1,l1;
            split_bf(aW[(size_t)k0*256 + p*16 + n], h0, l0);
            split_bf(aW[(size_t)(k0+1)*256 + p*16 + n], h1, l1);
            H.u[i2] = h0 | (h1<<16);
            L.u[i2] = l0 | (l1<<16);
        }
        BwaH[j] = H.s; BwaL[j] = L.s;
    }
    const float bb  = bias[gcol];
    const float vj  = av[p*16 + gd];
    const float abj = ab[p*16 + gd];

    // consumer mapping: thread tid reads words j=0..15 at hx[..][j][tid];
    // word j = (batch pbase+(j>>3), dim po*8+(j&7))
    const int po    = tid >> 3;        // dim octet 0..31
    const int pbase = (tid & 7) * 2;   // even batch
    const int wa0 = (po>>2)*1024 + ((po&3)*16 + pbase)*16;
    const int wa1 = wa0 + 16;

    // producer mapping: (batch gb, global dim D) -> slot (j_pub, tau)
    const int D = p*16 + gd;
    const int tau   = (gb>>1) | ((D>>3)<<3);
    const int j_pub = ((gb&1)<<3) | (D&7);

    const int xb = l & 15;
    const int xoct = l >> 4;           // 0..3: frag k-octet within kstep

    float c_state = 0.f, h1v = 0.f, h2v = 0.f;
    float m_run = -1.0e30f, l_run = 0.f, ctx = 0.f;

    float* zl = (float*)(smem + Z_OF);
    float* el = (float*)(smem + E_OF);

    for (int t = 0; t < SS; ++t) {
        const int par = t & 1;
        // ---- x loads first -----------------------------------------------
        const float* xrow = x + ((size_t)(b0 + xb) * SS + t) * II + xoct*8;
        float xv0[8], xv1[8];
        *(float4*)&xv0[0] = *(const float4*)(xrow);
        *(float4*)&xv0[4] = *(const float4*)(xrow + 4);
        *(float4*)&xv1[0] = *(const float4*)(xrow + 32);
        *(float4*)&xv1[4] = *(const float4*)(xrow + 36);

        // ---- issue coalesced tagged h(t-1) loads (j-interleaved) ---------
        ull hv[16]; ull spr = 0;
        const ull* hr = hx + ((size_t)(((t-1)&1)*NG + g) * 16) * 256 + tid;
        if (t > 0) {
            #pragma unroll
            for (int j = 0; j < 16; ++j) hv[j] = cld(hr + j*256);
        }
        ull* spp = spx + (size_t)par*4096 + g*256 + gb*16 + gd;
        if (t > 1) spr = cld(spp);

        // ---- x pack + x MFMA (overlaps h-load flight & store visibility) -
        short8 XH0, XL0, XH1, XL1;
        pack8(xv0, XH0, XL0);
        pack8(xv1, XH1, XL1);
        f32x4 zacc = {bb,bb,bb,bb};
        zacc = MFMA(XH0, BwiH[0], zacc);
        zacc = MFMA(XH0, BwiL[0], zacc);
        zacc = MFMA(XL0, BwiH[0], zacc);
        zacc = MFMA(XH1, BwiH[1], zacc);
        zacc = MFMA(XH1, BwiL[1], zacc);
        zacc = MFMA(XL1, BwiH[1], zacc);

        // ---- tag check + coalesced retry rounds --------------------------
        if (t > 0) {
            const unsigned texp = (unsigned)t;   // h(t-1) tagged t
            unsigned need = 0xFFFFu;
            int rounds = 0;
            while (true) {
                unsigned nn = 0;
                #pragma unroll
                for (int e = 0; e < 16; ++e)
                    if (need & (1u<<e))
                        if ((unsigned)(hv[e]>>32) != texp) nn |= (1u<<e);
                need = nn;
                if (!need || sdead) break;
                if (++rounds > H_CAP) { sdead = 1; break; }
                #pragma unroll
                for (int e = 0; e < 16; ++e)
                    if (need & (1u<<e)) hv[e] = cld(hr + e*256);
            }
            float va[16];
            #pragma unroll
            for (int e = 0; e < 16; ++e) va[e] = __uint_as_float((unsigned)hv[e]);
            short8 H0,L0,H1,L1;
            pack8(&va[0], H0, L0);
            pack8(&va[8], H1, L1);
            *(short8*)(smem + A_HI + wa0) = H0;
            *(short8*)(smem + A_LO + wa0) = L0;
            *(short8*)(smem + A_HI + wa1) = H1;
            *(short8*)(smem + A_LO + wa1) = L1;
        }
        __syncthreads();                                   // barrier A

        // ---- MFMA: z += h@Wh, energy partial -----------------------------
        f32x4 zacc1 = {0.f,0.f,0.f,0.f};
        f32x4 eacc  = {0.f,0.f,0.f,0.f};
        if (t > 0) {
            #pragma unroll
            for (int ks = 0; ks < 8; ++ks) {
                short8 ah = *(const short8*)(smem + A_HI + ks*1024 + l*16);
                short8 al = *(const short8*)(smem + A_LO + ks*1024 + l*16);
                if ((ks & 1) == 0) {
                    zacc = MFMA(ah, BwhH[ks], zacc);
                    zacc = MFMA(ah, BwhL[ks], zacc);
                    zacc = MFMA(al, BwhH[ks], zacc);
                } else {
                    zacc1 = MFMA(ah, BwhH[ks], zacc1);
                    zacc1 = MFMA(ah, BwhL[ks], zacc1);
                    zacc1 = MFMA(al, BwhH[ks], zacc1);
                }
                if ((ks>>1) == w) {
                    int jj = ks & 1;
                    eacc = MFMA(ah, BwaH[jj], eacc);
                    eacc = MFMA(ah, BwaL[jj], eacc);
                    eacc = MFMA(al, BwaH[jj], eacc);
                }
            }
        }
        #pragma unroll
        for (int r = 0; r < 4; ++r) zl[w*256 + r*64 + l] = zacc[r] + zacc1[r];
        if (t > 0) {
            #pragma unroll
            for (int r = 0; r < 4; ++r) el[w*256 + r*64 + l] = eacc[r];
        }
        __syncthreads();                                   // barrier B

        // ---- gates -------------------------------------------------------
        float z0 = zl[0*256 + w*64 + l];
        float z1 = zl[1*256 + w*64 + l];
        float z2 = zl[2*256 + w*64 + l];
        float z3 = zl[3*256 + w*64 + l];
        float ig = fsig(z0), fg = fsig(z1), gv = ftanh(z2), og = fsig(z3);
        c_state = fg*c_state + ig*gv;
        float h = og * ftanh(c_state);

        // ---- publish h(t) tagged t+1, fire-and-forget (critical path) ----
        cst(hx + ((size_t)(par*NG + g) * 16 + j_pub) * 256 + tau,
            ((ull)(unsigned)(t+1) << 32) | (ull)__float_as_uint(h));

        // ---- off critical path: score partial t-1, softmax update t-2 ----
        if (t > 0) {
            float e = el[0*256+w*64+l] + el[1*256+w*64+l]
                    + el[2*256+w*64+l] + el[3*256+w*64+l] + abj;
            float scp = vj * ftanh(e);
            scp += __shfl_xor(scp,1); scp += __shfl_xor(scp,2);
            scp += __shfl_xor(scp,4); scp += __shfl_xor(scp,8);
            if (gd == 0)
                cst(spx + (size_t)((t-1)&1)*4096 + g*256 + gb*16 + p,
                    ((ull)(unsigned)t << 32) | (ull)__float_as_uint(scp));
        }
        if (t > 1) {
            const unsigned texp = (unsigned)(t-1);
            int it = 0;
            while ((unsigned)(spr>>32) != texp) {
                if (sdead || ++it > SP_CAP) { sdead = 1; break; }
                spr = cld(spp);
            }
            float s = __uint_as_float((unsigned)spr);
            s += __shfl_xor(s,1); s += __shfl_xor(s,2);
            s += __shfl_xor(s,4); s += __shfl_xor(s,8);
            float m_new = fmaxf(m_run, s);
            float sc = __expf(m_run - m_new);
            float wt = __expf(s - m_new);
            l_run = l_run*sc + wt;
            ctx   = ctx*sc + wt*h2v;
            m_run = m_new;
        }
        h2v = h1v; h1v = h;
    }

    // ---- epilogue A: energy/score for SS-1, softmax update for SS-2 ------
    {
        const ull* hr = hx + ((size_t)(((SS-1)&1)*NG + g) * 16) * 256 + tid;
        ull hv[16];
        #pragma unroll
        for (int j = 0; j < 16; ++j) hv[j] = cld(hr + j*256);
        const unsigned texp = (unsigned)SS;
        unsigned need = 0xFFFFu;
        int rounds = 0;
        while (true) {
            unsigned nn = 0;
            #pragma unroll
            for (int e = 0; e < 16; ++e)
                if (need & (1u<<e))
                    if ((unsigned)(hv[e]>>32) != texp) nn |= (1u<<e);
            need = nn;
            if (!need || sdead) break;
            if (++rounds > H_CAP) { sdead = 1; break; }
            #pragma unroll
            for (int e = 0; e < 16; ++e)
                if (need & (1u<<e)) hv[e] = cld(hr + e*256);
        }
        float va[16];
        #pragma unroll
        for (int e = 0; e < 16; ++e) va[e] = __uint_as_float((unsigned)hv[e]);
        short8 H0,L0,H1,L1;
        pack8(&va[0], H0, L0);
        pack8(&va[8], H1, L1);
        *(short8*)(smem + A_HI + wa0) = H0;
        *(short8*)(smem + A_LO + wa0) = L0;
        *(short8*)(smem + A_HI + wa1) = H1;
        *(short8*)(smem + A_LO + wa1) = L1;
        __syncthreads();

        f32x4 eacc = {0.f,0.f,0.f,0.f};
        #pragma unroll
        for (int ks = 0; ks < 8; ++ks) {
            if ((ks>>1) == w) {
                short8 ah = *(const short8*)(smem + A_HI + ks*1024 + l*16);
                short8 al = *(const short8*)(smem + A_LO + ks*1024 + l*16);
                int jj = ks & 1;
                eacc = MFMA(ah, BwaH[jj], eacc);
                eacc = MFMA(ah, BwaL[jj], eacc);
                eacc = MFMA(al, BwaH[jj], eacc);
            }
        }
        #pragma unroll
        for (int r = 0; r < 4; ++r) el[w*256 + r*64 + l] = eacc[r];
        __syncthreads();

        {   // softmax update for SS-2 (sp slot SS&1, tag SS-1)
            ull* spp2 = spx + (size_t)(SS&1)*4096 + g*256 + gb*16 + gd;
            ull spr = cld(spp2);
            const unsigned te2 = (unsigned)(SS-1);
            int it = 0;
            while ((unsigned)(spr>>32) != te2) {
                if (sdead || ++it > SP_CAP) { sdead = 1; break; }
                spr = cld(spp2);
            }
            float s = __uint_as_float((unsigned)spr);
            s += __shfl_xor(s,1); s += __shfl_xor(s,2);
            s += __shfl_xor(s,4); s += __shfl_xor(s,8);
            float m_new = fmaxf(m_run, s);
            float sc = __expf(m_run - m_new);
            float wt = __expf(s - m_new);
            l_run = l_run*sc + wt;
            ctx   = ctx*sc + wt*h2v;
            m_run = m_new;
        }
        h2v = h1v;
        // score for SS-1 (tag SS)
        float e = el[0*256+w*64+l] + el[1*256+w*64+l]
                + el[2*256+w*64+l] + el[3*256+w*64+l] + abj;
        float scp = vj * ftanh(e);
        scp += __shfl_xor(scp,1); scp += __shfl_xor(scp,2);
        scp += __shfl_xor(scp,4); scp += __shfl_xor(scp,8);
        if (gd == 0)
            cst(spx + (size_t)((SS-1)&1)*4096 + g*256 + gb*16 + p,
                ((ull)(unsigned)SS << 32) | (ull)__float_as_uint(scp));
    }

    // ---- epilogue B: softmax update for SS-1, write context --------------
    {
        ull* spp2 = spx + (size_t)((SS-1)&1)*4096 + g*256 + gb*16 + gd;
        ull spr = cld(spp2);
        const unsigned texp = (unsigned)SS;
        int it = 0;
        while ((unsigned)(spr>>32) != texp) {
            if (sdead || ++it > SP_CAP) { sdead = 1; break; }
            spr = cld(spp2);
        }
        float s = __uint_as_float((unsigned)spr);
        s += __shfl_xor(s,1); s += __shfl_xor(s,2);
        s += __shfl_xor(s,4); s += __shfl_xor(s,8);
        float m_new = fmaxf(m_run, s);
        float sc = __expf(m_run - m_new);
        float wt = __expf(s - m_new);
        l_run = l_run*sc + wt;
        ctx   = ctx*sc + wt*h2v;   // h2v == h(SS-1)

        ctxg[(size_t)(b0+gb)*HH + p*16 + gd] = ctx / l_run;
    }
}

// ---------------------------------------------------------------------------
__global__ __launch_bounds__(64)
void finalize_kernel(const float* __restrict__ ctxg, const float* __restrict__ fcW,
                     const float* __restrict__ fcb, float* __restrict__ out)
{
    __shared__ float cs[HH];
    const int b = blockIdx.x, tid = threadIdx.x;
    *(float4*)&cs[tid*4] = *(const float4*)&ctxg[(size_t)b*HH + tid*4];
    __syncthreads();
    if (tid < OO) {
        float a = fcb[tid];
        #pragma unroll 8
        for (int d = 0; d < HH; ++d) a = fmaf(cs[d], fcW[d*OO + tid], a);
        out[b*OO + tid] = a;
    }
}

// ---------------------------------------------------------------------------
extern "C" void kernel_launch(void* const* d_in, const int* in_sizes, int n_in,
                              void* d_out, int out_size, void* d_ws, size_t ws_size,
                              hipStream_t stream)
{
    const float* x      = (const float*)d_in[0];
    const float* Wi     = (const float*)d_in[1];
    const float* Wh     = (const float*)d_in[2];
    const float* bias   = (const float*)d_in[3];
    const float* attn_W = (const float*)d_in[4];
    const float* attn_b = (const float*)d_in[5];
    const float* v      = (const float*)d_in[6];
    const float* fc_W   = (const float*)d_in[7];
    const float* fc_b   = (const float*)d_in[8];
    float* out = (float*)d_out;

    // workspace: tagged h ring (1MB, consumer-interleaved) + tagged sp ring + ctx
    ull*   hx   = (ull*)d_ws;                  // 2*NG*16*256 = 131072 ull
    ull*   spx  = hx + 2*NG*16*256;            // 2*NG*256    = 8192 ull
    float* ctxg = (float*)(spx + 8192);        // 65536 floats

    // zero all tags each launch (graph-replay + poison safe)
    hipMemsetAsync(hx, 0, (2*NG*16*256 + 8192) * sizeof(ull), stream);

    lstm_fused_kernel<<<dim3(NG*NP), dim3(256), 0, stream>>>(
        x, Wi, Wh, bias, attn_W, attn_b, v, hx, spx, ctxg);
    finalize_kernel<<<dim3(BB), dim3(64), 0, stream>>>(ctxg, fc_W, fc_b, out);
}